// Round 2
// baseline (1579.758 us; speedup 1.0000x reference)
//
#include <hip/hip_runtime.h>
#include <hip/hip_bf16.h>
#include <math.h>

#define NTOK   65536
#define L_SEQ  16384

typedef __bf16 bf16_t;
typedef bf16_t bf16x8 __attribute__((ext_vector_type(8)));
typedef float  f32x4  __attribute__((ext_vector_type(4)));

__device__ inline float phi_f(float x) { return x > 0.f ? x + 1.f : __expf(x); }

__device__ inline float quad_sum(float v) {
    v += __shfl_xor(v, 1);
    v += __shfl_xor(v, 2);
    v += __shfl_xor(v, 4);
    v += __shfl_xor(v, 8);
    return v;
}

// load element i from a buffer that is fp32 (f32=1) or bf16 (f32=0)
__device__ inline float ld_any(const void* p, int i, int f32) {
    return f32 ? ((const float*)p)[i] : (float)((const bf16_t*)p)[i];
}

// ------------------------------------------------- K-1: dtype probe
// Read first 4096 halfwords of x as bf16. Real bf16 data: |v| <= ~4.
// fp32 data misread as bf16: random exponent bytes -> |v| > 1000 (or NaN)
// almost surely. flag=1 => inputs are fp32.
__global__ __launch_bounds__(256) void k_detect(const void* __restrict__ xraw,
                                                int* __restrict__ flag) {
    __shared__ int bad;
    if (threadIdx.x == 0) bad = 0;
    __syncthreads();
    const bf16_t* xb = (const bf16_t*)xraw;
    int mybad = 0;
#pragma unroll
    for (int j = 0; j < 16; ++j) {
        float v = fabsf((float)xb[threadIdx.x + 256 * j]);
        if (!(v <= 1000.f)) mybad = 1;   // catches >1000 and NaN
    }
    if (mybad) atomicOr(&bad, 1);
    __syncthreads();
    if (threadIdx.x == 0) *flag = bad;
}

// ------------------------------------------------- K0a: convert x -> canonical bf16
__global__ __launch_bounds__(256) void k_convert(const void* __restrict__ xraw,
                                                 const int* __restrict__ flag,
                                                 bf16_t* __restrict__ xbf) {
    const int f = *flag;
    size_t i = ((size_t)blockIdx.x * 256 + threadIdx.x) * 4;
    if (f) {
        const float* src = (const float*)xraw;
#pragma unroll
        for (int j = 0; j < 4; ++j) xbf[i + j] = (bf16_t)src[i + j];
    } else {
        const bf16_t* src = (const bf16_t*)xraw;
#pragma unroll
        for (int j = 0; j < 4; ++j) xbf[i + j] = src[i + j];
    }
}

// ------------------------------------------------- K0b: weight transpose + bias pack
// Wqkv_t[768][256] / Wo_t[256][256] / W1_t[1024][256] / W2_t[256][1024] in
// [N][K] layout (k-contiguous rows for MFMA B-fragments); biases -> pbuf;
// zero fp32 KV state.
__global__ __launch_bounds__(256) void k_prep(
    const void* __restrict__ Wq, const void* __restrict__ Wk,
    const void* __restrict__ Wv, const void* __restrict__ Wo,
    const void* __restrict__ W1, const void* __restrict__ W2,
    const void* __restrict__ bq, const void* __restrict__ bk,
    const void* __restrict__ bv, const void* __restrict__ bo,
    const void* __restrict__ b1, const void* __restrict__ b2,
    const void* __restrict__ g1, const void* __restrict__ be1,
    const void* __restrict__ g2, const void* __restrict__ be2,
    const int* __restrict__ flag,
    bf16_t* __restrict__ Wqkv_t, bf16_t* __restrict__ Wo_t,
    bf16_t* __restrict__ W1_t, bf16_t* __restrict__ W2_t,
    bf16_t* __restrict__ pbuf, float* __restrict__ kvbuf) {
    const int f = *flag;
    int idx = blockIdx.x * 256 + threadIdx.x;
    if (idx < 196608) {                       // Wqkv_t [768][256]
        int n = idx >> 8, k = idx & 255;
        float v;
        if (n < 256)      v = ld_any(Wq, k * 256 + n, f);
        else if (n < 512) v = ld_any(Wk, k * 256 + (n - 256), f);
        else              v = ld_any(Wv, k * 256 + (n - 512), f);
        Wqkv_t[idx] = (bf16_t)v;
    } else if (idx < 262144) {                // Wo_t [256][256]
        int i = idx - 196608; int n = i >> 8, k = i & 255;
        Wo_t[i] = (bf16_t)ld_any(Wo, k * 256 + n, f);
    } else if (idx < 524288) {                // W1_t [1024][256]
        int i = idx - 262144; int n = i >> 8, k = i & 255;
        W1_t[i] = (bf16_t)ld_any(W1, k * 1024 + n, f);
    } else if (idx < 786432) {                // W2_t [256][1024]
        int i = idx - 524288; int n = i >> 10, k = i & 1023;
        W2_t[i] = (bf16_t)ld_any(W2, k * 256 + n, f);
    } else if (idx < 820224) {                // KV state zero-init
        kvbuf[idx - 786432] = 0.f;
    } else if (idx < 823552) {                // bias/param pack (3328 elems)
        int i = idx - 820224;
        float v;
        if (i < 256)        v = ld_any(bq, i, f);
        else if (i < 512)   v = ld_any(bk, i - 256, f);
        else if (i < 768)   v = ld_any(bv, i - 512, f);
        else if (i < 1024)  v = ld_any(bo, i - 768, f);
        else if (i < 2048)  v = ld_any(b1, i - 1024, f);
        else if (i < 2304)  v = ld_any(b2, i - 2048, f);
        else if (i < 2560)  v = ld_any(g1, i - 2304, f);
        else if (i < 2816)  v = ld_any(be1, i - 2560, f);
        else if (i < 3072)  v = ld_any(g2, i - 2816, f);
        else                v = ld_any(be2, i - 3072, f);
        pbuf[i] = (bf16_t)v;
    }
}

// ------------------------------------------------- K1: QKV GEMM + phi
// grid (NTOK/64, 768/64); block 256 = 4 waves
__global__ __launch_bounds__(256) void k_qkv(
    const bf16_t* __restrict__ x, const bf16_t* __restrict__ Wqkv_t,
    const bf16_t* __restrict__ pbuf,
    bf16_t* __restrict__ q_phi, bf16_t* __restrict__ k_phi,
    bf16_t* __restrict__ v_out) {
    const int mt = blockIdx.x, nt = blockIdx.y;
    const int tid = threadIdx.x, wave = tid >> 6, lane = tid & 63;
    const int l15 = lane & 15, quad = lane >> 4;
    __shared__ __align__(16) bf16_t xs[64][264];
    const int m0 = mt * 64;
    for (int c = tid; c < 2048; c += 256) {
        int r = c >> 5, col = (c & 31) * 8;
        *(bf16x8*)&xs[r][col] = *(const bf16x8*)&x[(size_t)(m0 + r) * 256 + col];
    }
    __syncthreads();
    const int mrow = wave * 16 + l15;
    const int kq = quad * 8;
    const int n0 = nt * 64;
    f32x4 acc[4] = {};
    for (int kk = 0; kk < 256; kk += 32) {
        bf16x8 a = *(const bf16x8*)&xs[mrow][kk + kq];
#pragma unroll
        for (int s = 0; s < 4; ++s) {
            bf16x8 b = *(const bf16x8*)&Wqkv_t[(size_t)(n0 + s * 16 + l15) * 256 + kk + kq];
            acc[s] = __builtin_amdgcn_mfma_f32_16x16x32_bf16(a, b, acc[s], 0, 0, 0);
        }
    }
#pragma unroll
    for (int s = 0; s < 4; ++s) {
        int ng = n0 + s * 16 + l15;
        bf16_t* dst = ng < 256 ? q_phi : (ng < 512 ? k_phi : v_out);
        int nl = ng & 255;
        float bias = (float)pbuf[(ng < 256 ? 0 : (ng < 512 ? 256 : 512)) + nl];
#pragma unroll
        for (int r = 0; r < 4; ++r) {
            int m = m0 + wave * 16 + quad * 4 + r;
            float val = acc[s][r] + bias;
            if (ng < 512) val = phi_f(val);
            dst[(size_t)m * 256 + nl] = (bf16_t)val;
        }
    }
}

// ------------------------------------------------- K2: KV state reduction
// grid 256 = 32 (b,h) * 8 L-chunks; fp32 atomics into kvbuf[bh][32*32 + 32]
__global__ __launch_bounds__(256) void k_kvsum(
    const bf16_t* __restrict__ k_phi, const bf16_t* __restrict__ v_in,
    float* __restrict__ kvbuf) {
    const int bid = blockIdx.x;
    const int bh = bid >> 3, ck = bid & 7;
    const int b = bh >> 3, h = bh & 7;
    const int tid = threadIdx.x;
    __shared__ float ks[8][33], vs[8][33];
    const int l0 = ck * 2048;
    const size_t base = ((size_t)b * L_SEQ + l0) * 256 + h * 32;
    const int i = tid >> 5, el = tid & 31;
    float acc[4] = {}, ksacc[4] = {};
    for (int lb = 0; lb < 2048; lb += 8) {
        ks[i][el] = (float)k_phi[base + (size_t)(lb + i) * 256 + el];
        vs[i][el] = (float)v_in[base + (size_t)(lb + i) * 256 + el];
        __syncthreads();
#pragma unroll
        for (int j = 0; j < 4; ++j) {
            int d = i + 8 * j;
#pragma unroll
            for (int ii = 0; ii < 8; ++ii) acc[j] += ks[ii][d] * vs[ii][el];
        }
        if (el == 0) {
#pragma unroll
            for (int j = 0; j < 4; ++j) {
                int d = i + 8 * j;
#pragma unroll
                for (int ii = 0; ii < 8; ++ii) ksacc[j] += ks[ii][d];
            }
        }
        __syncthreads();
    }
    float* kvdst = kvbuf + (size_t)bh * 1056;
#pragma unroll
    for (int j = 0; j < 4; ++j) {
        int d = i + 8 * j;
        atomicAdd(&kvdst[d * 32 + el], acc[j]);
        if (el == 0) atomicAdd(&kvdst[1024 + d], ksacc[j]);
    }
}

// ------------------------------------------------- K3: apply attention
__global__ __launch_bounds__(256) void k_apply(
    const bf16_t* __restrict__ q_phi, const float* __restrict__ kvbuf,
    bf16_t* __restrict__ attn) {
    const int bid = blockIdx.x;
    const int bh = bid >> 3, ck = bid & 7;
    const int b = bh >> 3, h = bh & 7;
    const int tid = threadIdx.x;
    __shared__ float kv[32][33];
    __shared__ float ksum[32];
    __shared__ float qs[8][33];
    const float* kvsrc = kvbuf + (size_t)bh * 1056;
    for (int idx = tid; idx < 1024; idx += 256) kv[idx >> 5][idx & 31] = kvsrc[idx];
    if (tid < 32) ksum[tid] = kvsrc[1024 + tid];
    __syncthreads();
    const int l0 = ck * 2048;
    const size_t base = ((size_t)b * L_SEQ + l0) * 256 + h * 32;
    const int i = tid >> 5, e = tid & 31;
    for (int lb = 0; lb < 2048; lb += 8) {
        qs[i][e] = (float)q_phi[base + (size_t)(lb + i) * 256 + e];
        __syncthreads();
        float num = 0.f, den = 0.f;
#pragma unroll
        for (int d = 0; d < 32; ++d) {
            float q = qs[i][d];
            num += q * kv[d][e];
            den += q * ksum[d];
        }
        attn[base + (size_t)(lb + i) * 256 + e] = (bf16_t)(num / (den + 1e-6f));
        __syncthreads();
    }
}

// ------------------------------------------------- K4: @Wo + x residual + LN1
__global__ __launch_bounds__(256) void k_wo_ln1(
    const bf16_t* __restrict__ attn, const bf16_t* __restrict__ Wo_t,
    const bf16_t* __restrict__ pbuf, const bf16_t* __restrict__ x_in,
    bf16_t* __restrict__ x1) {
    const int mt = blockIdx.x;
    const int tid = threadIdx.x, wave = tid >> 6, lane = tid & 63;
    const int l15 = lane & 15, quad = lane >> 4;
    __shared__ __align__(16) bf16_t as[64][264];
    const int m0 = mt * 64;
    for (int c = tid; c < 2048; c += 256) {
        int r = c >> 5, col = (c & 31) * 8;
        *(bf16x8*)&as[r][col] = *(const bf16x8*)&attn[(size_t)(m0 + r) * 256 + col];
    }
    __syncthreads();
    const int mrow = wave * 16 + l15;
    const int kq = quad * 8;
    f32x4 acc[16] = {};
    for (int kk = 0; kk < 256; kk += 32) {
        bf16x8 a = *(const bf16x8*)&as[mrow][kk + kq];
#pragma unroll
        for (int s = 0; s < 16; ++s) {
            bf16x8 b = *(const bf16x8*)&Wo_t[(size_t)(s * 16 + l15) * 256 + kk + kq];
            acc[s] = __builtin_amdgcn_mfma_f32_16x16x32_bf16(a, b, acc[s], 0, 0, 0);
        }
    }
    float s1[4] = {}, s2[4] = {};
#pragma unroll
    for (int s = 0; s < 16; ++s) {
        int n = s * 16 + l15;
        float bias = (float)pbuf[768 + n];
#pragma unroll
        for (int r = 0; r < 4; ++r) {
            int mr = wave * 16 + quad * 4 + r;
            float val = acc[s][r] + bias + (float)x_in[(size_t)(m0 + mr) * 256 + n];
            acc[s][r] = val;
            s1[r] += val; s2[r] += val * val;
        }
    }
#pragma unroll
    for (int r = 0; r < 4; ++r) {
        float ts = quad_sum(s1[r]), ts2 = quad_sum(s2[r]);
        float mu = ts * (1.f / 256.f);
        float rs = rsqrtf(ts2 * (1.f / 256.f) - mu * mu + 1e-5f);
        s1[r] = mu; s2[r] = rs;
    }
#pragma unroll
    for (int s = 0; s < 16; ++s) {
        int n = s * 16 + l15;
        float gn = (float)pbuf[2304 + n], bn = (float)pbuf[2560 + n];
#pragma unroll
        for (int r = 0; r < 4; ++r) {
            int m = m0 + wave * 16 + quad * 4 + r;
            x1[(size_t)m * 256 + n] = (bf16_t)((acc[s][r] - s1[r]) * s2[r] * gn + bn);
        }
    }
}

// ------------------------------------------------- K5: fused FFN + LN2 (+dual-dtype store)
__global__ __launch_bounds__(256) void k_ff_ln2(
    const bf16_t* __restrict__ x1, const bf16_t* __restrict__ W1_t,
    const bf16_t* __restrict__ W2_t, const bf16_t* __restrict__ pbuf,
    const int* __restrict__ flag, void* __restrict__ out) {
    const int f32o = *flag;
    const int mt = blockIdx.x;
    const int tid = threadIdx.x, wave = tid >> 6, lane = tid & 63;
    const int l15 = lane & 15, quad = lane >> 4;
    __shared__ __align__(16) bf16_t xs[64][264];
    __shared__ __align__(16) bf16_t hs[64][72];
    const int m0 = mt * 64;
    for (int c = tid; c < 2048; c += 256) {
        int r = c >> 5, col = (c & 31) * 8;
        *(bf16x8*)&xs[r][col] = *(const bf16x8*)&x1[(size_t)(m0 + r) * 256 + col];
    }
    __syncthreads();
    const int mrow = wave * 16 + l15;
    const int kq = quad * 8;
    f32x4 acc[16] = {};
    for (int ch = 0; ch < 16; ++ch) {
        f32x4 hacc[4] = {};
        for (int kk = 0; kk < 256; kk += 32) {
            bf16x8 a = *(const bf16x8*)&xs[mrow][kk + kq];
#pragma unroll
            for (int s = 0; s < 4; ++s) {
                bf16x8 b = *(const bf16x8*)&W1_t[(size_t)(ch * 64 + s * 16 + l15) * 256 + kk + kq];
                hacc[s] = __builtin_amdgcn_mfma_f32_16x16x32_bf16(a, b, hacc[s], 0, 0, 0);
            }
        }
#pragma unroll
        for (int s = 0; s < 4; ++s) {
            int n = ch * 64 + s * 16 + l15;
            float bias = (float)pbuf[1024 + n];
#pragma unroll
            for (int r = 0; r < 4; ++r) {
                int mr = wave * 16 + quad * 4 + r;
                float val = hacc[s][r] + bias;
                hs[mr][s * 16 + l15] = (bf16_t)(val > 0.f ? val : 0.f);
            }
        }
        __syncthreads();
        for (int kk = 0; kk < 64; kk += 32) {
            bf16x8 a = *(const bf16x8*)&hs[mrow][kk + kq];
#pragma unroll
            for (int s = 0; s < 16; ++s) {
                bf16x8 b = *(const bf16x8*)&W2_t[(size_t)(s * 16 + l15) * 1024 + ch * 64 + kk + kq];
                acc[s] = __builtin_amdgcn_mfma_f32_16x16x32_bf16(a, b, acc[s], 0, 0, 0);
            }
        }
        __syncthreads();
    }
    float s1[4] = {}, s2[4] = {};
#pragma unroll
    for (int s = 0; s < 16; ++s) {
        int n = s * 16 + l15;
        float bias = (float)pbuf[2048 + n];
#pragma unroll
        for (int r = 0; r < 4; ++r) {
            int mr = wave * 16 + quad * 4 + r;
            float val = acc[s][r] + bias + (float)xs[mr][n];
            acc[s][r] = val;
            s1[r] += val; s2[r] += val * val;
        }
    }
#pragma unroll
    for (int r = 0; r < 4; ++r) {
        float ts = quad_sum(s1[r]), ts2 = quad_sum(s2[r]);
        float mu = ts * (1.f / 256.f);
        float rs = rsqrtf(ts2 * (1.f / 256.f) - mu * mu + 1e-5f);
        s1[r] = mu; s2[r] = rs;
    }
#pragma unroll
    for (int s = 0; s < 16; ++s) {
        int n = s * 16 + l15;
        float gn = (float)pbuf[2816 + n], bn = (float)pbuf[3072 + n];
#pragma unroll
        for (int r = 0; r < 4; ++r) {
            int m = m0 + wave * 16 + quad * 4 + r;
            float val = (acc[s][r] - s1[r]) * s2[r] * gn + bn;
            if (f32o) ((float*)out)[(size_t)m * 256 + n] = val;
            else      ((bf16_t*)out)[(size_t)m * 256 + n] = (bf16_t)val;
        }
    }
}

// ------------------------------------------------- launch
extern "C" void kernel_launch(void* const* d_in, const int* in_sizes, int n_in,
                              void* d_out, int out_size, void* d_ws, size_t ws_size,
                              hipStream_t stream) {
    char* ws = (char*)d_ws;
    int*    flag   = (int*)ws;                              // 4 B (256 reserved)
    bf16_t* xbf    = (bf16_t*)(ws + 256);                   // 16.7M elems
    bf16_t* Wqkv_t = (bf16_t*)(ws + 33554688);              // 196608
    bf16_t* Wo_t   = (bf16_t*)(ws + 33947904);              // 65536
    bf16_t* W1_t   = (bf16_t*)(ws + 34078976);              // 262144
    bf16_t* W2_t   = (bf16_t*)(ws + 34603264);              // 262144
    bf16_t* pbuf   = (bf16_t*)(ws + 35127552);              // 3328
    float*  kvbuf  = (float*)(ws + 35134208);               // 33792 f32
    bf16_t* bufQ   = (bf16_t*)(ws + 35269376);              // 16.7M elems
    bf16_t* bufK   = bufQ + (size_t)NTOK * 256;
    bf16_t* bufV   = bufK + (size_t)NTOK * 256;
    bf16_t* bufAttn = bufK;   // K dead after k_kvsum
    bf16_t* bufX1   = bufQ;   // Q dead after k_apply

    k_detect<<<1, 256, 0, stream>>>(d_in[0], flag);
    k_convert<<<16384, 256, 0, stream>>>(d_in[0], flag, xbf);
    k_prep<<<3217, 256, 0, stream>>>(d_in[1], d_in[3], d_in[5], d_in[7],
                                     d_in[9], d_in[11],
                                     d_in[2], d_in[4], d_in[6], d_in[8],
                                     d_in[10], d_in[12],
                                     d_in[13], d_in[14], d_in[15], d_in[16],
                                     flag, Wqkv_t, Wo_t, W1_t, W2_t, pbuf, kvbuf);
    k_qkv<<<dim3(NTOK / 64, 12), 256, 0, stream>>>(xbf, Wqkv_t, pbuf,
                                                   bufQ, bufK, bufV);
    k_kvsum<<<256, 256, 0, stream>>>(bufK, bufV, kvbuf);
    k_apply<<<256, 256, 0, stream>>>(bufQ, kvbuf, bufAttn);
    k_wo_ln1<<<NTOK / 64, 256, 0, stream>>>(bufAttn, Wo_t, pbuf, xbf, bufX1);
    k_ff_ln2<<<NTOK / 64, 256, 0, stream>>>(bufX1, W1_t, W2_t, pbuf, flag, d_out);
}

// Round 4
// 540.780 us; speedup vs baseline: 2.9213x; 2.9213x over previous
//
#include <hip/hip_runtime.h>
#include <hip/hip_bf16.h>
#include <math.h>

#define NTOK   65536
#define L_SEQ  16384

typedef __bf16 bf16_t;
typedef bf16_t bf16x8 __attribute__((ext_vector_type(8)));
typedef bf16_t bf16x4 __attribute__((ext_vector_type(4)));
typedef float  f32x4  __attribute__((ext_vector_type(4)));

__device__ inline float phi_f(float x) { return x > 0.f ? x + 1.f : __expf(x); }

__device__ inline float quad_sum(float v) {
    v += __shfl_xor(v, 1);
    v += __shfl_xor(v, 2);
    v += __shfl_xor(v, 4);
    v += __shfl_xor(v, 8);
    return v;
}

__device__ inline float ld_any(const void* p, size_t i, int f32) {
    return f32 ? ((const float*)p)[i] : (float)((const bf16_t*)p)[i];
}

// async 16B global->LDS (direct-to-shared DMA; HW dest = wave-uniform base +
// lane*16 — callers below always pass lds ptrs of exactly that shape)
__device__ inline void async_copy16(const bf16_t* g, bf16_t* l) {
    __builtin_amdgcn_global_load_lds(
        (const __attribute__((address_space(1))) unsigned int*)g,
        (__attribute__((address_space(3))) unsigned int*)l, 16, 0, 0);
}

// Stage nslot 16-B units (8 bf16 each; nslot = elements/8) of a
// [rows][rowstride] bf16 slice into LDS with an XOR swizzle of the
// (1<<ulog2) units per row: phys j = u ^ (n & (U-1)).
__device__ inline void stage_swz(const bf16_t* __restrict__ g, bf16_t* lds,
                                 int tid, int nslot, int ulog2, int rowstride) {
    const int umask = (1 << ulog2) - 1;
    for (int s = tid; s < nslot; s += 256) {
        int n = s >> ulog2, j = s & umask;
        int u = j ^ (n & umask);
        async_copy16(g + (size_t)n * rowstride + u * 8, lds + (size_t)s * 8);
    }
}

__device__ inline bf16x8 rd_swz(const bf16_t* lds, int n, int u, int ulog2) {
    int j = u ^ (n & ((1 << ulog2) - 1));
    return *(const bf16x8*)&lds[(((size_t)n << ulog2) + j) * 8];
}

// A-frags for one wave: row m, k = kk*32 + quad*8, kk=0..7 (K=256)
__device__ inline void ld_afrags(const bf16_t* __restrict__ tile, int row, int q8,
                                 bf16x8 a[8]) {
#pragma unroll
    for (int kk = 0; kk < 8; ++kk)
        a[kk] = *(const bf16x8*)&tile[(size_t)row * 256 + kk * 32 + q8];
}

// ------------------------------------------------- K-1: dtype probe
__global__ __launch_bounds__(256) void k_detect(const void* __restrict__ xraw,
                                                int* __restrict__ flag) {
    __shared__ int bad;
    if (threadIdx.x == 0) bad = 0;
    __syncthreads();
    const bf16_t* xb = (const bf16_t*)xraw;
    int mybad = 0;
#pragma unroll
    for (int j = 0; j < 16; ++j) {
        float v = fabsf((float)xb[threadIdx.x + 256 * j]);
        if (!(v <= 1000.f)) mybad = 1;
    }
    if (mybad) atomicOr(&bad, 1);
    __syncthreads();
    if (threadIdx.x == 0) *flag = bad;
}

// ------------------------------------------------- K0a: x -> canonical bf16
__global__ __launch_bounds__(256) void k_convert(const void* __restrict__ xraw,
                                                 const int* __restrict__ flag,
                                                 bf16_t* __restrict__ xbf) {
    const int f = *flag;
    size_t i = ((size_t)blockIdx.x * 256 + threadIdx.x) * 4;
    if (f) {
        f32x4 v = *(const f32x4*)((const float*)xraw + i);
        bf16x4 o;
#pragma unroll
        for (int j = 0; j < 4; ++j) o[j] = (bf16_t)v[j];
        *(bf16x4*)&xbf[i] = o;
    } else {
        *(bf16x4*)&xbf[i] = *(const bf16x4*)((const bf16_t*)xraw + i);
    }
}

// ------------------------------------------------- K0b: weight transpose + bias pack
__global__ __launch_bounds__(256) void k_prep(
    const void* __restrict__ Wq, const void* __restrict__ Wk,
    const void* __restrict__ Wv, const void* __restrict__ Wo,
    const void* __restrict__ W1, const void* __restrict__ W2,
    const void* __restrict__ bq, const void* __restrict__ bk,
    const void* __restrict__ bv, const void* __restrict__ bo,
    const void* __restrict__ b1, const void* __restrict__ b2,
    const void* __restrict__ g1, const void* __restrict__ be1,
    const void* __restrict__ g2, const void* __restrict__ be2,
    const int* __restrict__ flag,
    bf16_t* __restrict__ Wqkv_t, bf16_t* __restrict__ Wo_t,
    bf16_t* __restrict__ W1_t, bf16_t* __restrict__ W2_t,
    bf16_t* __restrict__ pbuf, float* __restrict__ kvbuf) {
    const int f = *flag;
    int idx = blockIdx.x * 256 + threadIdx.x;
    if (idx < 196608) {                       // Wqkv_t [768][256]
        int n = idx >> 8, k = idx & 255;
        float v;
        if (n < 256)      v = ld_any(Wq, k * 256 + n, f);
        else if (n < 512) v = ld_any(Wk, k * 256 + (n - 256), f);
        else              v = ld_any(Wv, k * 256 + (n - 512), f);
        Wqkv_t[idx] = (bf16_t)v;
    } else if (idx < 262144) {                // Wo_t [256][256]
        int i = idx - 196608; int n = i >> 8, k = i & 255;
        Wo_t[i] = (bf16_t)ld_any(Wo, k * 256 + n, f);
    } else if (idx < 524288) {                // W1_t [1024][256]
        int i = idx - 262144; int n = i >> 8, k = i & 255;
        W1_t[i] = (bf16_t)ld_any(W1, k * 1024 + n, f);
    } else if (idx < 786432) {                // W2_t [256][1024]
        int i = idx - 524288; int n = i >> 10, k = i & 1023;
        W2_t[i] = (bf16_t)ld_any(W2, k * 256 + n, f);
    } else if (idx < 820224) {                // KV state zero-init
        kvbuf[idx - 786432] = 0.f;
    } else if (idx < 823552) {                // bias/param pack
        int i = idx - 820224;
        float v;
        if (i < 256)        v = ld_any(bq, i, f);
        else if (i < 512)   v = ld_any(bk, i - 256, f);
        else if (i < 768)   v = ld_any(bv, i - 512, f);
        else if (i < 1024)  v = ld_any(bo, i - 768, f);
        else if (i < 2048)  v = ld_any(b1, i - 1024, f);
        else if (i < 2304)  v = ld_any(b2, i - 2048, f);
        else if (i < 2560)  v = ld_any(g1, i - 2304, f);
        else if (i < 2816)  v = ld_any(be1, i - 2560, f);
        else if (i < 3072)  v = ld_any(g2, i - 2816, f);
        else                v = ld_any(be2, i - 3072, f);
        pbuf[i] = (bf16_t)v;
    }
}

// ------------------------------------------------- K1: QKV GEMM + phi
// grid (1024, 6): M=64, N=128 per block. A stationary in regs, B via
// global_load_lds. Tile 128x256 = 4096 slots (= elements/8).
__global__ __launch_bounds__(256) void k_qkv(
    const bf16_t* __restrict__ x, const bf16_t* __restrict__ Wqkv_t,
    const bf16_t* __restrict__ pbuf,
    bf16_t* __restrict__ q_phi, bf16_t* __restrict__ k_phi,
    bf16_t* __restrict__ v_out) {
    const int mt = blockIdx.x, nt = blockIdx.y;
    const int tid = threadIdx.x, wave = tid >> 6, lane = tid & 63;
    const int l15 = lane & 15, quad = lane >> 4, q8 = quad * 8;
    __shared__ __align__(16) bf16_t bs[128 * 256];
    const int m0 = mt * 64;
    bf16x8 a[8];
    ld_afrags(x + (size_t)m0 * 256, wave * 16 + l15, q8, a);
    stage_swz(Wqkv_t + (size_t)nt * 128 * 256, bs, tid, 4096, 5, 256);
    __syncthreads();
    f32x4 acc[8] = {};
#pragma unroll
    for (int kk = 0; kk < 8; ++kk) {
#pragma unroll
        for (int s = 0; s < 8; ++s) {
            bf16x8 b = rd_swz(bs, s * 16 + l15, kk * 4 + quad, 5);
            acc[s] = __builtin_amdgcn_mfma_f32_16x16x32_bf16(a[kk], b, acc[s], 0, 0, 0);
        }
    }
#pragma unroll
    for (int s = 0; s < 8; ++s) {
        int ng = nt * 128 + s * 16 + l15;
        bf16_t* dst = ng < 256 ? q_phi : (ng < 512 ? k_phi : v_out);
        int nl = ng & 255;
        float bias = (float)pbuf[(ng < 256 ? 0 : (ng < 512 ? 256 : 512)) + nl];
#pragma unroll
        for (int r = 0; r < 4; ++r) {
            int m = m0 + wave * 16 + quad * 4 + r;
            float val = acc[s][r] + bias;
            if (ng < 512) val = phi_f(val);
            dst[(size_t)m * 256 + nl] = (bf16_t)val;
        }
    }
}

// ------------------------------------------------- K2: KV state reduction
__global__ __launch_bounds__(256) void k_kvsum(
    const bf16_t* __restrict__ k_phi, const bf16_t* __restrict__ v_in,
    float* __restrict__ kvbuf) {
    const int bid = blockIdx.x;
    const int bh = bid >> 6, ck = bid & 63;
    const int b = bh >> 3, h = bh & 7;
    const int tid = threadIdx.x;
    __shared__ float ks[32][33], vs[32][33];
    const size_t base = ((size_t)b * L_SEQ + ck * 256) * 256 + h * 32;
    const int row = tid >> 3, c4 = (tid & 7) * 4;
    const int d = row, e4 = c4;
    float acc[4] = {}, ksacc = 0.f;
    for (int it = 0; it < 8; ++it) {
        bf16x4 kk4 = *(const bf16x4*)&k_phi[base + (size_t)(it * 32 + row) * 256 + c4];
        bf16x4 vv4 = *(const bf16x4*)&v_in[base + (size_t)(it * 32 + row) * 256 + c4];
#pragma unroll
        for (int j = 0; j < 4; ++j) { ks[row][c4 + j] = (float)kk4[j]; vs[row][c4 + j] = (float)vv4[j]; }
        __syncthreads();
#pragma unroll
        for (int ii = 0; ii < 32; ++ii) {
            float kd = ks[ii][d];
            ksacc += kd;
#pragma unroll
            for (int j = 0; j < 4; ++j) acc[j] += kd * vs[ii][e4 + j];
        }
        __syncthreads();
    }
    float* kvdst = kvbuf + (size_t)bh * 1056;
#pragma unroll
    for (int j = 0; j < 4; ++j) atomicAdd(&kvdst[d * 32 + e4 + j], acc[j]);
    if ((tid & 7) == 0) atomicAdd(&kvdst[1024 + d], ksacc);
}

// ------------------------------------------------- K3: apply attention
__global__ __launch_bounds__(256) void k_apply(
    const bf16_t* __restrict__ q_phi, const float* __restrict__ kvbuf,
    bf16_t* __restrict__ attn) {
    const int bid = blockIdx.x;
    const int bh = bid >> 6, ck = bid & 63;
    const int b = bh >> 3, h = bh & 7;
    const int tid = threadIdx.x;
    __shared__ float kv[32][33];
    __shared__ float ksumS[32];
    __shared__ float qs[32][33];
    const float* kvsrc = kvbuf + (size_t)bh * 1056;
    for (int idx = tid; idx < 1024; idx += 256) kv[idx >> 5][idx & 31] = kvsrc[idx];
    if (tid < 32) ksumS[tid] = kvsrc[1024 + tid];
    __syncthreads();
    const size_t base = ((size_t)b * L_SEQ + ck * 256) * 256 + h * 32;
    const int row = tid >> 3, c4 = (tid & 7) * 4;
    for (int it = 0; it < 8; ++it) {
        bf16x4 q4 = *(const bf16x4*)&q_phi[base + (size_t)(it * 32 + row) * 256 + c4];
#pragma unroll
        for (int j = 0; j < 4; ++j) qs[row][c4 + j] = (float)q4[j];
        __syncthreads();
        float num[4] = {}, den = 0.f;
#pragma unroll
        for (int dd = 0; dd < 32; ++dd) {
            float q = qs[row][dd];
            den += q * ksumS[dd];
#pragma unroll
            for (int j = 0; j < 4; ++j) num[j] += q * kv[dd][c4 + j];
        }
        float inv = 1.f / (den + 1e-6f);
        bf16x4 o;
#pragma unroll
        for (int j = 0; j < 4; ++j) o[j] = (bf16_t)(num[j] * inv);
        *(bf16x4*)&attn[base + (size_t)(it * 32 + row) * 256 + c4] = o;
        __syncthreads();
    }
}

// ------------------------------------------------- K4: @Wo + x residual + LN1
// 64x256 chunk = 2048 slots per ping-pong buffer.
__global__ __launch_bounds__(256) void k_wo_ln1(
    const bf16_t* __restrict__ attn, const bf16_t* __restrict__ Wo_t,
    const bf16_t* __restrict__ pbuf, const void* __restrict__ xraw,
    const int* __restrict__ flag, bf16_t* __restrict__ x1) {
    const int f = *flag;
    const int mt = blockIdx.x;
    const int tid = threadIdx.x, wave = tid >> 6, lane = tid & 63;
    const int l15 = lane & 15, quad = lane >> 4, q8 = quad * 8;
    __shared__ __align__(16) bf16_t wos[2][16384];
    const int m0 = mt * 64;
    bf16x8 a[8];
    ld_afrags(attn + (size_t)m0 * 256, wave * 16 + l15, q8, a);
    stage_swz(Wo_t, wos[0], tid, 2048, 5, 256);
    __syncthreads();
    f32x4 acc[16] = {};
    for (int nc = 0; nc < 4; ++nc) {
        if (nc < 3) stage_swz(Wo_t + (size_t)(nc + 1) * 64 * 256, wos[(nc + 1) & 1],
                              tid, 2048, 5, 256);
        const bf16_t* buf = wos[nc & 1];
#pragma unroll
        for (int kk = 0; kk < 8; ++kk) {
#pragma unroll
            for (int s = 0; s < 4; ++s) {
                bf16x8 b = rd_swz(buf, s * 16 + l15, kk * 4 + quad, 5);
                acc[nc * 4 + s] = __builtin_amdgcn_mfma_f32_16x16x32_bf16(a[kk], b, acc[nc * 4 + s], 0, 0, 0);
            }
        }
        __syncthreads();   // publishes next chunk, protects current from overwrite
    }
    float s1[4] = {}, s2[4] = {};
#pragma unroll
    for (int s = 0; s < 16; ++s) {
        int n = s * 16 + l15;
        float bias = (float)pbuf[768 + n];
#pragma unroll
        for (int r = 0; r < 4; ++r) {
            int m = m0 + wave * 16 + quad * 4 + r;
            float val = acc[s][r] + bias + ld_any(xraw, (size_t)m * 256 + n, f);
            acc[s][r] = val;
            s1[r] += val; s2[r] += val * val;
        }
    }
#pragma unroll
    for (int r = 0; r < 4; ++r) {
        float ts = quad_sum(s1[r]), ts2 = quad_sum(s2[r]);
        float mu = ts * (1.f / 256.f);
        float rs = rsqrtf(ts2 * (1.f / 256.f) - mu * mu + 1e-5f);
        s1[r] = mu; s2[r] = rs;
    }
#pragma unroll
    for (int s = 0; s < 16; ++s) {
        int n = s * 16 + l15;
        float gn = (float)pbuf[2304 + n], bn = (float)pbuf[2560 + n];
#pragma unroll
        for (int r = 0; r < 4; ++r) {
            int m = m0 + wave * 16 + quad * 4 + r;
            x1[(size_t)m * 256 + n] = (bf16_t)((acc[s][r] - s1[r]) * s2[r] * gn + bn);
        }
    }
}

// ------------------------------------------------- K5: fused FFN + LN2
// w1s chunk 64x256 = 2048 slots; w2s chunk 256x64 = 2048 slots.
__global__ __launch_bounds__(256) void k_ff_ln2(
    const bf16_t* __restrict__ x1, const bf16_t* __restrict__ W1_t,
    const bf16_t* __restrict__ W2_t, const bf16_t* __restrict__ pbuf,
    const int* __restrict__ flag, void* __restrict__ out) {
    const int f32o = *flag;
    const int mt = blockIdx.x;
    const int tid = threadIdx.x, wave = tid >> 6, lane = tid & 63;
    const int l15 = lane & 15, quad = lane >> 4, q8 = quad * 8;
    __shared__ __align__(16) bf16_t w1s[16384];
    __shared__ __align__(16) bf16_t w2s[16384];
    __shared__ __align__(16) bf16_t hs[4][16][72];
    const int m0 = mt * 64;
    bf16x8 a[8];
    ld_afrags(x1 + (size_t)m0 * 256, wave * 16 + l15, q8, a);
    stage_swz(W1_t, w1s, tid, 2048, 5, 256);
    __syncthreads();
    f32x4 acc[16] = {};
    for (int ch = 0; ch < 16; ++ch) {
        stage_swz(W2_t + ch * 64, w2s, tid, 2048, 3, 1024);   // prefetch W2 chunk
        // step a: h = relu(x1 @ W1_chunk + b1)
        f32x4 hacc[4] = {};
#pragma unroll
        for (int kk = 0; kk < 8; ++kk) {
#pragma unroll
            for (int s = 0; s < 4; ++s) {
                bf16x8 b = rd_swz(w1s, s * 16 + l15, kk * 4 + quad, 5);
                hacc[s] = __builtin_amdgcn_mfma_f32_16x16x32_bf16(a[kk], b, hacc[s], 0, 0, 0);
            }
        }
#pragma unroll
        for (int s = 0; s < 4; ++s) {
            float bias = (float)pbuf[1024 + ch * 64 + s * 16 + l15];
#pragma unroll
            for (int r = 0; r < 4; ++r) {
                float val = hacc[s][r] + bias;
                hs[wave][quad * 4 + r][s * 16 + l15] = (bf16_t)(val > 0.f ? val : 0.f);
            }
        }
        // wave-local C->A layout round-trip (in-order DS pipe within wave)
        bf16x8 a2_0 = *(const bf16x8*)&hs[wave][l15][q8];
        bf16x8 a2_1 = *(const bf16x8*)&hs[wave][l15][32 + q8];
        __syncthreads();                         // w2s ready; w1s fully consumed
        if (ch < 15) stage_swz(W1_t + (size_t)(ch + 1) * 64 * 256, w1s, tid, 2048, 5, 256);
#pragma unroll
        for (int s = 0; s < 16; ++s) {
            bf16x8 b0 = rd_swz(w2s, s * 16 + l15, quad, 3);
            acc[s] = __builtin_amdgcn_mfma_f32_16x16x32_bf16(a2_0, b0, acc[s], 0, 0, 0);
            bf16x8 b1v = rd_swz(w2s, s * 16 + l15, 4 + quad, 3);
            acc[s] = __builtin_amdgcn_mfma_f32_16x16x32_bf16(a2_1, b1v, acc[s], 0, 0, 0);
        }
        __syncthreads();                         // w1s(ch+1) ready; w2s consumed
    }
    // epilogue: + b2 + x1 residual, LN2, dual-dtype store
    float s1[4] = {}, s2[4] = {};
#pragma unroll
    for (int s = 0; s < 16; ++s) {
        int n = s * 16 + l15;
        float bias = (float)pbuf[2048 + n];
#pragma unroll
        for (int r = 0; r < 4; ++r) {
            int m = m0 + wave * 16 + quad * 4 + r;
            float val = acc[s][r] + bias + (float)x1[(size_t)m * 256 + n];
            acc[s][r] = val;
            s1[r] += val; s2[r] += val * val;
        }
    }
#pragma unroll
    for (int r = 0; r < 4; ++r) {
        float ts = quad_sum(s1[r]), ts2 = quad_sum(s2[r]);
        float mu = ts * (1.f / 256.f);
        float rs = rsqrtf(ts2 * (1.f / 256.f) - mu * mu + 1e-5f);
        s1[r] = mu; s2[r] = rs;
    }
#pragma unroll
    for (int s = 0; s < 16; ++s) {
        int n = s * 16 + l15;
        float gn = (float)pbuf[2816 + n], bn = (float)pbuf[3072 + n];
#pragma unroll
        for (int r = 0; r < 4; ++r) {
            int m = m0 + wave * 16 + quad * 4 + r;
            float val = (acc[s][r] - s1[r]) * s2[r] * gn + bn;
            if (f32o) ((float*)out)[(size_t)m * 256 + n] = val;
            else      ((bf16_t*)out)[(size_t)m * 256 + n] = (bf16_t)val;
        }
    }
}

// ------------------------------------------------- launch
extern "C" void kernel_launch(void* const* d_in, const int* in_sizes, int n_in,
                              void* d_out, int out_size, void* d_ws, size_t ws_size,
                              hipStream_t stream) {
    char* ws = (char*)d_ws;
    int*    flag   = (int*)ws;                              // 4 B (256 reserved)
    bf16_t* xbf    = (bf16_t*)(ws + 256);                   // 16.7M elems
    bf16_t* Wqkv_t = (bf16_t*)(ws + 33554688);              // 196608
    bf16_t* Wo_t   = (bf16_t*)(ws + 33947904);              // 65536
    bf16_t* W1_t   = (bf16_t*)(ws + 34078976);              // 262144
    bf16_t* W2_t   = (bf16_t*)(ws + 34603264);              // 262144
    bf16_t* pbuf   = (bf16_t*)(ws + 35127552);              // 3328
    float*  kvbuf  = (float*)(ws + 35134208);               // 33792 f32
    bf16_t* bufQ   = (bf16_t*)(ws + 35269376);              // 16.7M elems
    bf16_t* bufK   = bufQ + (size_t)NTOK * 256;
    bf16_t* bufV   = bufK + (size_t)NTOK * 256;
    bf16_t* bufAttn = bufK;   // K dead after k_kvsum
    bf16_t* bufX1   = bufQ;   // Q dead after k_apply

    k_detect<<<1, 256, 0, stream>>>(d_in[0], flag);
    k_convert<<<16384, 256, 0, stream>>>(d_in[0], flag, xbf);
    k_prep<<<3217, 256, 0, stream>>>(d_in[1], d_in[3], d_in[5], d_in[7],
                                     d_in[9], d_in[11],
                                     d_in[2], d_in[4], d_in[6], d_in[8],
                                     d_in[10], d_in[12],
                                     d_in[13], d_in[14], d_in[15], d_in[16],
                                     flag, Wqkv_t, Wo_t, W1_t, W2_t, pbuf, kvbuf);
    k_qkv<<<dim3(1024, 6), 256, 0, stream>>>(xbf, Wqkv_t, pbuf, bufQ, bufK, bufV);
    k_kvsum<<<2048, 256, 0, stream>>>(bufK, bufV, kvbuf);
    k_apply<<<2048, 256, 0, stream>>>(bufQ, kvbuf, bufAttn);
    k_wo_ln1<<<1024, 256, 0, stream>>>(bufAttn, Wo_t, pbuf, d_in[0], flag, bufX1);
    k_ff_ln2<<<1024, 256, 0, stream>>>(bufX1, W1_t, W2_t, pbuf, flag, d_out);
}